// Round 3
// baseline (56.498 us; speedup 1.0000x reference)
//
#include <hip/hip_runtime.h>

#define NRES  300
#define NTRJ  20
#define NBINS 34
#define PLANE (NTRJ * NRES * 3)   // 18000 floats per output tensor
#define IC     10                 // i's per chunk (column part)
#define NCHUNK 30                 // 300 / IC
#define TILEF  (64 * NBINS)       // 2176 floats per staged gw row
#define NCOLB  (5 * 5 * NCHUNK)   // 750 column blocks

__device__ __forceinline__ float wred(float v) {
#pragma unroll
  for (int m = 32; m; m >>= 1) v += __shfl_xor(v, m, 64);
  return v;
}

__global__ __launch_bounds__(256)
void force_kernel(const float* __restrict__ cO,
                  const float* __restrict__ cCB,
                  const float* __restrict__ cH,
                  const float* __restrict__ gw,
                  const float* __restrict__ hmin,
                  const float* __restrict__ hmax,
                  float* __restrict__ out) {
  float* accO  = out + 2 * PLANE;
  float* accCB = out + 3 * PLANE;
  float* accH  = out + 4 * PLANE;
  const int tid  = threadIdx.x;
  const int wv   = tid >> 6;
  const int lane = tid & 63;
  const int bx   = blockIdx.x;

  __shared__ float wlds[2][TILEF];

  if (bx < NCOLB) {
    // ============ column part: lane = j, wave = b, serial loop over i =======
    // outputs accs_CB[b,j] and accs_O[b,j] accumulated in registers (no shuffles)
    const int jt = bx % 5;
    const int bg = (bx / 5) % 5;
    const int ch = bx / 25;            // 0..29
    const int i0 = ch * IC;
    const int b  = bg * 4 + wv;
    const int j  = jt * 64 + lane;
    const bool jv = (j < NRES);
    const int jc = jv ? j : NRES - 1;
    const int F  = (jt == 4) ? (NRES - 256) * NBINS : TILEF;  // valid floats/row

    // zero-fill LDS tail once (tile 4) so invalid lanes read 0s, not garbage
    if (F < TILEF) {
      for (int e = F + tid; e < TILEF; e += 256) { wlds[0][e] = 0.f; wlds[1][e] = 0.f; }
    }

    // per-thread fixed coords (lane's j)
    const float* pj = cCB + ((size_t)b * NRES + jc) * 3;
    const float pjx = pj[0], pjy = pj[1], pjz = pj[2];
    const float* po = cO + ((size_t)b * NRES + jc) * 3;
    const float pox = po[0], poy = po[1], poz = po[2];

    float acx = 0.f, acy = 0.f, acz = 0.f;   // accs_CB partial
    float aox = 0.f, aoy = 0.f, aoz = 0.f;   // accs_O  partial

    // prefetch gw row i0 into registers
    float r[9];
    {
      const float* gr = gw + ((size_t)i0 * NRES + jt * 64) * NBINS;
#pragma unroll
      for (int q = 0; q < 9; ++q) { int e = tid + q * 256; r[q] = (e < F) ? gr[e] : 0.f; }
    }

    int p = 0;
    for (int ii = 0; ii < IC; ++ii) {
      const int i = i0 + ii;
      // write staged row, one barrier per iteration (1-deep skew is safe)
#pragma unroll
      for (int q = 0; q < 9; ++q) { int e = tid + q * 256; if (e < F) wlds[p][e] = r[q]; }
      __syncthreads();
      // issue next row's global loads early; latency hides under compute
      if (ii + 1 < IC) {
        const float* g2 = gw + ((size_t)(i + 1) * NRES + jt * 64) * NBINS;
#pragma unroll
        for (int q = 0; q < 9; ++q) { int e = tid + q * 256; r[q] = (e < F) ? g2[e] : 0.f; }
      }

      // my j's weight row from LDS
      float w[NBINS];
      const float2* p2 = (const float2*)(wlds[p] + lane * NBINS);
#pragma unroll
      for (int k = 0; k < 17; ++k) { float2 v = p2[k]; w[2*k] = v.x; w[2*k+1] = v.y; }

      // ---- CB distogram force (3-segment gaussian recurrence) ----
      const float* pi = cCB + ((size_t)b * NRES + i) * 3;
      float dx = pjx - pi[0], dy = pjy - pi[1], dz = pjz - pi[2];
      float d2 = fmaf(dx, dx, fmaf(dy, dy, dz * dz));
      d2 = fminf(fmaxf(d2, 0.01f), 1600.0f);
      float rinv = __frsqrt_rn(d2);
      float d    = d2 * rinv;

      float dA = d - 3.75f, dB = d - 9.75f, dC = d - 15.75f;
      float gA = __expf(-0.32f * dA * dA), mA = __expf(fmaf(0.32f, dA, -0.08f));
      float gB = __expf(-0.32f * dB * dB), mB = __expf(fmaf(0.32f, dB, -0.08f));
      float gC = __expf(-0.32f * dC * dC), mC = __expf(fmaf(0.32f, dC, -0.08f));
      float s0 = 0.f, s1 = 0.f, s2 = 0.f;
#pragma unroll
      for (int k = 0; k < 10; ++k) {
        s0 = fmaf(w[k]      * dA, gA, s0); gA *= mA; mA *= 0.85214379f; dA -= 0.5f;
        s1 = fmaf(w[k + 12] * dB, gB, s1); gB *= mB; mB *= 0.85214379f; dB -= 0.5f;
        s2 = fmaf(w[k + 24] * dC, gC, s2); gC *= mC; mC *= 0.85214379f; dC -= 0.5f;
      }
      s0 = fmaf(w[10] * dA, gA, s0); gA *= mA; dA -= 0.5f;
      s1 = fmaf(w[22] * dB, gB, s1); gB *= mB; dB -= 0.5f;
      s0 = fmaf(w[11] * dA, gA, s0);
      s1 = fmaf(w[23] * dB, gB, s1);
      float cf = 76.8f * ((s0 + s1) + s2) * rinv;
      acx = fmaf(cf, dx, acx); acy = fmaf(cf, dy, acy); acz = fmaf(cf, dz, acz);

      // ---- HB restraint column sum -> accs_O ----
      const float* ph = cH + ((size_t)b * NRES + i) * 3;
      float ex = pox - ph[0], ey = poy - ph[1], ez = poz - ph[2];
      float e2 = fmaf(ex, ex, fmaf(ey, ey, ez * ez));
      e2 = fminf(fmaxf(e2, 0.01f), 1600.0f);
      float rh = __frsqrt_rn(e2);
      float dh = e2 * rh;
      float hmn = hmin[(size_t)i * NRES + jc];
      float hmx = hmax[(size_t)i * NRES + jc];
      float vmin = fmaxf(hmn - dh, 0.0f);
      float vmax = fmaxf(dh - hmx, 0.0f);
      float fmn = 15.0f * vmin;
      float fmx = (vmax > 0.0f) ? 5.0f * __powf(vmax, 0.75f) : 0.0f;
      float ff = (fmn - fmx) * rh;
      aox = fmaf(ff, ex, aox); aoy = fmaf(ff, ey, aoy); aoz = fmaf(ff, ez, aoz);

      p ^= 1;
    }

    if (jv) {
      const int base = (b * NRES + j) * 3;
      atomicAdd(&accCB[base + 0], acx);
      atomicAdd(&accCB[base + 1], acy);
      atomicAdd(&accCB[base + 2], acz);
      atomicAdd(&accO[base + 0], aox);
      atomicAdd(&accO[base + 1], aoy);
      atomicAdd(&accO[base + 2], aoz);
    }
  } else {
    // ============ row part: accs_H[b,i] = -sum_j pair_hb (cheap) ============
    const int unit = (bx - NCOLB) * 4 + wv;     // 0..1499
    const int i  = unit % NRES;
    const int jt = unit / NRES;                 // 0..4
    const int jj = jt * 64 + lane;
    const bool valid = (jj < NRES);
    const int jc = valid ? jj : NRES - 1;

    const float hmn = hmin[(size_t)i * NRES + jc];
    const float hmx = hmax[(size_t)i * NRES + jc];

    for (int b = 0; b < NTRJ; ++b) {
      const float* ph = cH + ((size_t)b * NRES + i) * 3;
      const float* po = cO + ((size_t)b * NRES + jc) * 3;
      float ex = po[0] - ph[0], ey = po[1] - ph[1], ez = po[2] - ph[2];
      float e2 = fmaf(ex, ex, fmaf(ey, ey, ez * ez));
      e2 = fminf(fmaxf(e2, 0.01f), 1600.0f);
      float rh = __frsqrt_rn(e2);
      float dh = e2 * rh;
      float vmin = fmaxf(hmn - dh, 0.0f);
      float vmax = fmaxf(dh - hmx, 0.0f);
      float fmn = 15.0f * vmin;
      float fmx = (vmax > 0.0f) ? 5.0f * __powf(vmax, 0.75f) : 0.0f;
      float ff = (fmn - fmx) * rh;
      float qx = -ff * ex, qy = -ff * ey, qz = -ff * ez;

      if (!valid) { qx = qy = qz = 0.0f; }

      qx = wred(qx); qy = wred(qy); qz = wred(qz);
      if (lane == 0) {
        int base = (b * NRES + i) * 3;
        atomicAdd(&accH[base + 0], qx);
        atomicAdd(&accH[base + 1], qy);
        atomicAdd(&accH[base + 2], qz);
      }
    }
  }
}

extern "C" void kernel_launch(void* const* d_in, const int* in_sizes, int n_in,
                              void* d_out, int out_size, void* d_ws, size_t ws_size,
                              hipStream_t stream) {
  // input order per setup_inputs(): N, C, O, CB, H, gaussian_weights, hb_min, hb_max
  const float* cO  = (const float*)d_in[2];
  const float* cCB = (const float*)d_in[3];
  const float* cH  = (const float*)d_in[4];
  const float* gw  = (const float*)d_in[5];
  const float* hmn = (const float*)d_in[6];
  const float* hmx = (const float*)d_in[7];
  float* out = (float*)d_out;

  // accs_N and accs_C are exactly zero (K_ANG_HB_GEN == 0); atomics need zeroed
  // accumulators -> zero the whole output every call (deterministic).
  hipMemsetAsync(out, 0, (size_t)out_size * sizeof(float), stream);

  // 750 column blocks (transposed, register-accumulated) + 375 row blocks
  force_kernel<<<dim3(NCOLB + 375), dim3(256), 0, stream>>>(
      cO, cCB, cH, gw, hmn, hmx, out);
}

// Round 4
// 55.890 us; speedup vs baseline: 1.0109x; 1.0109x over previous
//
#include <hip/hip_runtime.h>

#define NRES  300
#define NTRJ  20
#define NBINS 34
#define PLANE (NTRJ * NRES * 3)   // 18000 floats per output tensor
#define NJT   19                  // j-tiles of 16 (ceil 300/16)
#define NCH   30                  // i-chunks
#define IC    10                  // i's per chunk

// One block = 16 j's x all 20 trajectories (5 waves x [4 b x 16 j] lanes).
// Each lane owns one (j,b): coords + accumulators live in registers for the
// whole block; gw rows are read straight from global (4-lane broadcast, L1
// reuse across the 5 waves, each row fetched from HBM exactly once device-wide).
// No LDS, no barriers. accs_H is fused via a 16-lane group reduce per i.
__global__ __launch_bounds__(320)
void force_kernel(const float* __restrict__ cO,
                  const float* __restrict__ cCB,
                  const float* __restrict__ cH,
                  const float* __restrict__ gw,
                  const float* __restrict__ hmin,
                  const float* __restrict__ hmax,
                  float* __restrict__ out) {
  float* accO  = out + 2 * PLANE;
  float* accCB = out + 3 * PLANE;
  float* accH  = out + 4 * PLANE;

  const int tid  = threadIdx.x;
  const int wv   = tid >> 6;          // wave 0..4
  const int lane = tid & 63;
  const int bsub = lane >> 4;         // 0..3
  const int jsub = lane & 15;         // 0..15
  const int bx   = blockIdx.x;
  const int jt   = bx % NJT;
  const int ch   = bx / NJT;          // 0..29
  const int i0   = ch * IC;
  const int b    = wv * 4 + bsub;     // 0..19
  const int j    = jt * 16 + jsub;
  const bool jv  = (j < NRES);
  const int jc   = jv ? j : NRES - 1;

  // per-lane fixed coords (this lane's j, b)
  const float* pj = cCB + ((size_t)(b * NRES + jc)) * 3;
  const float pjx = pj[0], pjy = pj[1], pjz = pj[2];
  const float* po = cO + ((size_t)(b * NRES + jc)) * 3;
  const float pox = po[0], poy = po[1], poz = po[2];

  float acx = 0.f, acy = 0.f, acz = 0.f;   // accs_CB[b,j] partial (sum over i)
  float aox = 0.f, aoy = 0.f, aoz = 0.f;   // accs_O [b,j] partial (sum over i)

  for (int ii = 0; ii < IC; ++ii) {
    const int i = i0 + ii;

    // gaussian weights for (i, j): 17 x b64 gather, 16 unique addrs/wave
    float w[NBINS];
    const float2* gp = (const float2*)(gw + ((size_t)i * NRES + jc) * NBINS);
#pragma unroll
    for (int k = 0; k < 17; ++k) { float2 v = gp[k]; w[2*k] = v.x; w[2*k+1] = v.y; }

    const float hmn = hmin[i * NRES + jc];
    const float hmx = hmax[i * NRES + jc];

    // ---- CB distogram force (3-segment gaussian recurrence) ----
    const float* pi = cCB + ((size_t)(b * NRES + i)) * 3;
    float dx = pjx - pi[0], dy = pjy - pi[1], dz = pjz - pi[2];
    float d2 = fmaf(dx, dx, fmaf(dy, dy, dz * dz));
    d2 = fminf(fmaxf(d2, 0.01f), 1600.0f);   // clamp d to [0.1, 40]
    float rinv = __frsqrt_rn(d2);
    float d    = d2 * rinv;

    float dA = d - 3.75f, dB = d - 9.75f, dC = d - 15.75f;
    float gA = __expf(-0.32f * dA * dA), mA = __expf(fmaf(0.32f, dA, -0.08f));
    float gB = __expf(-0.32f * dB * dB), mB = __expf(fmaf(0.32f, dB, -0.08f));
    float gC = __expf(-0.32f * dC * dC), mC = __expf(fmaf(0.32f, dC, -0.08f));
    float s0 = 0.f, s1 = 0.f, s2 = 0.f;
#pragma unroll
    for (int k = 0; k < 10; ++k) {
      s0 = fmaf(w[k]      * dA, gA, s0); gA *= mA; mA *= 0.85214379f; dA -= 0.5f;
      s1 = fmaf(w[k + 12] * dB, gB, s1); gB *= mB; mB *= 0.85214379f; dB -= 0.5f;
      s2 = fmaf(w[k + 24] * dC, gC, s2); gC *= mC; mC *= 0.85214379f; dC -= 0.5f;
    }
    s0 = fmaf(w[10] * dA, gA, s0); gA *= mA; dA -= 0.5f;
    s1 = fmaf(w[22] * dB, gB, s1); gB *= mB; dB -= 0.5f;
    s0 = fmaf(w[11] * dA, gA, s0);
    s1 = fmaf(w[23] * dB, gB, s1);
    float cf = 76.8f * ((s0 + s1) + s2) * rinv;   // 150/sigma^3 = 76.8
    acx = fmaf(cf, dx, acx); acy = fmaf(cf, dy, acy); acz = fmaf(cf, dz, acz);

    // ---- HB min/max restraint (O_j - H_i) ----
    const float* ph = cH + ((size_t)(b * NRES + i)) * 3;
    float ex = pox - ph[0], ey = poy - ph[1], ez = poz - ph[2];
    float e2 = fmaf(ex, ex, fmaf(ey, ey, ez * ez));
    e2 = fminf(fmaxf(e2, 0.01f), 1600.0f);
    float rh = __frsqrt_rn(e2);
    float dh = e2 * rh;
    float vmin = fmaxf(hmn - dh, 0.0f);
    float vmax = fmaxf(dh - hmx, 0.0f);
    float fmn = 15.0f * vmin;                               // 3*5*v^1
    float fmx = (vmax > 0.0f) ? 5.0f * __powf(vmax, 0.75f) : 0.0f;
    float ff = (fmn - fmx) * rh;
    aox = fmaf(ff, ex, aox); aoy = fmaf(ff, ey, aoy); aoz = fmaf(ff, ez, aoz);

    // ---- fused accs_H[b,i]: reduce pair_hb over the 16-lane jsub group ----
    float qx = jv ? ff * ex : 0.f;
    float qy = jv ? ff * ey : 0.f;
    float qz = jv ? ff * ez : 0.f;
#pragma unroll
    for (int m = 1; m < 16; m <<= 1) {
      qx += __shfl_xor(qx, m, 64);
      qy += __shfl_xor(qy, m, 64);
      qz += __shfl_xor(qz, m, 64);
    }
    if (jsub == 0) {
      const int hb = (b * NRES + i) * 3;
      atomicAdd(&accH[hb + 0], -qx);
      atomicAdd(&accH[hb + 1], -qy);
      atomicAdd(&accH[hb + 2], -qz);
    }
  }

  if (jv) {
    const int base = (b * NRES + j) * 3;
    atomicAdd(&accCB[base + 0], acx);
    atomicAdd(&accCB[base + 1], acy);
    atomicAdd(&accCB[base + 2], acz);
    atomicAdd(&accO[base + 0], aox);
    atomicAdd(&accO[base + 1], aoy);
    atomicAdd(&accO[base + 2], aoz);
  }
}

extern "C" void kernel_launch(void* const* d_in, const int* in_sizes, int n_in,
                              void* d_out, int out_size, void* d_ws, size_t ws_size,
                              hipStream_t stream) {
  // input order per setup_inputs(): N, C, O, CB, H, gaussian_weights, hb_min, hb_max
  const float* cO  = (const float*)d_in[2];
  const float* cCB = (const float*)d_in[3];
  const float* cH  = (const float*)d_in[4];
  const float* gw  = (const float*)d_in[5];
  const float* hmn = (const float*)d_in[6];
  const float* hmx = (const float*)d_in[7];
  float* out = (float*)d_out;

  // accs_N and accs_C are exactly zero (K_ANG_HB_GEN == 0); atomics need zeroed
  // accumulators -> zero the whole output every call (deterministic).
  hipMemsetAsync(out, 0, (size_t)out_size * sizeof(float), stream);

  force_kernel<<<dim3(NJT * NCH), dim3(320), 0, stream>>>(
      cO, cCB, cH, gw, hmn, hmx, out);
}